// Round 1
// baseline (6583.150 us; speedup 1.0000x reference)
//
#include <hip/hip_runtime.h>
#include <math.h>

#define D 128
#define EPSV 1e-6f
#define CLIP_HI 1e6f

// ---------------- Phase 1: per-block column partial sums of xA, xB ----------
__global__ void colsum_partial(const float* __restrict__ xA, const float* __restrict__ xB,
                               int NA, int NB,
                               float* __restrict__ partA, float* __restrict__ partB) {
    int c = threadIdx.x;   // 0..127 (column)
    int b = blockIdx.x;
    float sa = 0.f, sb = 0.f;
    for (int r = b; r < NA; r += gridDim.x) sa += xA[(size_t)r * D + c];
    for (int r = b; r < NB; r += gridDim.x) sb += xB[(size_t)r * D + c];
    partA[(size_t)b * D + c] = sa;
    partB[(size_t)b * D + c] = sb;
}

// ---------------- Phase 2: reduce partials, compute alpha -------------------
__global__ void compute_alpha(const float* __restrict__ partA, const float* __restrict__ partB,
                              int G, int NA, int NB,
                              const float* __restrict__ fc1_w, const float* __restrict__ fc1_b,
                              const float* __restrict__ fc2_w, const float* __restrict__ fc2_b,
                              float* __restrict__ alpha_out) {
    __shared__ float g[D];
    __shared__ float h[D];
    int c = threadIdx.x;  // 0..127
    float sa = 0.f, sb = 0.f;
    for (int b = 0; b < G; ++b) {
        sa += partA[(size_t)b * D + c];
        sb += partB[(size_t)b * D + c];
    }
    g[c] = 0.5f * (sa / (float)NA + sb / (float)NB);
    __syncthreads();
    // h[j] = tanh(sum_k g[k] * fc1_w[j,k] + fc1_b[j])
    float acc = fc1_b[c];
    for (int k = 0; k < D; ++k) acc += g[k] * fc1_w[(size_t)c * D + k];
    h[c] = tanhf(acc);
    __syncthreads();
    if (c == 0) {
        float a = fc2_b[0];
        for (int k = 0; k < D; ++k) a += h[k] * fc2_w[k];
        a = 1.f / (1.f + expf(-a));                 // sigmoid
        a = fminf(fmaxf(a, EPSV), 1.f - EPSV);      // clip
        *alpha_out = a;
    }
}

// ---------------- Scatter: msg[dst] += cur[src] * att[e] --------------------
// edges layout: edges[0..E) = src, edges[E..2E) = dst
__global__ void scatter_add(const float* __restrict__ cur, const float* __restrict__ att,
                            const int* __restrict__ edges, int E,
                            float* __restrict__ msg) {
    const long long total = (long long)E * (D / 4);  // one thread per 4-float chunk
    long long stride = (long long)gridDim.x * blockDim.x;
    for (long long idx = (long long)blockIdx.x * blockDim.x + threadIdx.x;
         idx < total; idx += stride) {
        int e  = (int)(idx >> 5);   // idx / 32
        int ch = (int)(idx & 31);   // idx % 32
        int src = edges[e];
        int dst = edges[E + e];
        float a = att[e];
        const float4 v = *reinterpret_cast<const float4*>(cur + (size_t)src * D + ch * 4);
        float* p = msg + (size_t)dst * D + ch * 4;
        atomicAdd(p + 0, v.x * a);
        atomicAdd(p + 1, v.y * a);
        atomicAdd(p + 2, v.z * a);
        atomicAdd(p + 3, v.w * a);
    }
}

// ---------------- Combine: out = clip(feat0*a + msg*(1-a)) ------------------
__global__ void combine(const float4* __restrict__ feat0, const float4* __restrict__ msg,
                        const float* __restrict__ alpha_p, float4* __restrict__ out, int n4) {
    float a = alpha_p[0];
    float b = 1.f - a;
    int stride = gridDim.x * blockDim.x;
    for (int i = blockIdx.x * blockDim.x + threadIdx.x; i < n4; i += stride) {
        float4 f = feat0[i];
        float4 m = msg[i];
        float4 r;
        r.x = fminf(fmaxf(f.x * a + m.x * b, EPSV), CLIP_HI);
        r.y = fminf(fmaxf(f.y * a + m.y * b, EPSV), CLIP_HI);
        r.z = fminf(fmaxf(f.z * a + m.z * b, EPSV), CLIP_HI);
        r.w = fminf(fmaxf(f.w * a + m.w * b, EPSV), CLIP_HI);
        out[i] = r;
    }
}

extern "C" void kernel_launch(void* const* d_in, const int* in_sizes, int n_in,
                              void* d_out, int out_size, void* d_ws, size_t ws_size,
                              hipStream_t stream) {
    const float* xA    = (const float*)d_in[0];
    const float* xB    = (const float*)d_in[1];
    const float* attAB = (const float*)d_in[2];
    const float* attBA = (const float*)d_in[3];
    const float* fc1_w = (const float*)d_in[4];
    const float* fc1_b = (const float*)d_in[5];
    const float* fc2_w = (const float*)d_in[6];
    const float* fc2_b = (const float*)d_in[7];
    const int*   eAB   = (const int*)d_in[8];   // src in A (first E), dst in B (next E)
    const int*   eBA   = (const int*)d_in[9];   // src in B, dst in A

    const int NA = in_sizes[0] / D;
    const int NB = in_sizes[1] / D;
    const int E  = in_sizes[2];

    float* out  = (float*)d_out;
    float* curA = out;                      // [NA, D]
    float* curB = out + (size_t)NA * D;     // [NB, D]

    const int G = 512;  // partial-sum blocks
    float* msgA  = (float*)d_ws;                    // NA*D
    float* msgB  = msgA + (size_t)NA * D;           // NB*D
    float* partA = msgB + (size_t)NB * D;           // G*D
    float* partB = partA + (size_t)G * D;           // G*D
    float* alpha = partB + (size_t)G * D;           // 1

    // alpha computation (tiny)
    colsum_partial<<<G, D, 0, stream>>>(xA, xB, NA, NB, partA, partB);
    compute_alpha<<<1, D, 0, stream>>>(partA, partB, G, NA, NB,
                                       fc1_w, fc1_b, fc2_w, fc2_b, alpha);

    const size_t msgBytes = ((size_t)NA + (size_t)NB) * D * sizeof(float);
    const int sc_blocks = 4096, sc_threads = 256;
    const int cb_blocks = 2048, cb_threads = 256;

    for (int hop = 0; hop < 3; ++hop) {
        hipMemsetAsync(msgA, 0, msgBytes, stream);
        const float* fA = (hop == 0) ? xA : curA;
        const float* fB = (hop == 0) ? xB : curB;
        // msgA <- sum over eBA of curB[src]*attBA ; msgB <- from curA via eAB
        scatter_add<<<sc_blocks, sc_threads, 0, stream>>>(fB, attBA, eBA, E, msgA);
        scatter_add<<<sc_blocks, sc_threads, 0, stream>>>(fA, attAB, eAB, E, msgB);
        combine<<<cb_blocks, cb_threads, 0, stream>>>((const float4*)xA, (const float4*)msgA,
                                                      alpha, (float4*)curA, NA * D / 4);
        combine<<<cb_blocks, cb_threads, 0, stream>>>((const float4*)xB, (const float4*)msgB,
                                                      alpha, (float4*)curB, NB * D / 4);
    }
}

// Round 2
// 751.349 us; speedup vs baseline: 8.7618x; 8.7618x over previous
//
#include <hip/hip_runtime.h>
#include <math.h>

#define D 128
#define EPSV 1e-6f
#define CLIP_HI 1e6f
#define G 512          // colsum partial blocks
#define RPB 8          // rows per block in aggregate (256 threads / 32 lanes)

// ---------------- alpha: per-block column partial sums ----------------------
__global__ void colsum_partial(const float* __restrict__ xA, const float* __restrict__ xB,
                               int NA, int NB,
                               float* __restrict__ partA, float* __restrict__ partB) {
    int c = threadIdx.x;   // 0..127 (column)
    int b = blockIdx.x;
    float sa = 0.f, sb = 0.f;
    for (int r = b; r < NA; r += gridDim.x) sa += xA[(size_t)r * D + c];
    for (int r = b; r < NB; r += gridDim.x) sb += xB[(size_t)r * D + c];
    partA[(size_t)b * D + c] = sa;
    partB[(size_t)b * D + c] = sb;
}

// ---------------- alpha: reduce partials + tiny MLP -------------------------
__global__ void compute_alpha(const float* __restrict__ partA, const float* __restrict__ partB,
                              int NA, int NB,
                              const float* __restrict__ fc1_w, const float* __restrict__ fc1_b,
                              const float* __restrict__ fc2_w, const float* __restrict__ fc2_b,
                              float* __restrict__ alpha_out) {
    __shared__ float g[D];
    __shared__ float h[D];
    int c = threadIdx.x;  // 0..127
    float sa = 0.f, sb = 0.f;
    for (int b = 0; b < G; ++b) {
        sa += partA[(size_t)b * D + c];
        sb += partB[(size_t)b * D + c];
    }
    g[c] = 0.5f * (sa / (float)NA + sb / (float)NB);
    __syncthreads();
    float acc = fc1_b[c];
    for (int k = 0; k < D; ++k) acc += g[k] * fc1_w[(size_t)c * D + k];
    h[c] = tanhf(acc);
    __syncthreads();
    if (c == 0) {
        float a = fc2_b[0];
        for (int k = 0; k < D; ++k) a += h[k] * fc2_w[k];
        a = 1.f / (1.f + expf(-a));
        a = fminf(fmaxf(a, EPSV), 1.f - EPSV);
        *alpha_out = a;
    }
}

// ---------------- CSR build --------------------------------------------------
// edges layout: edges[0..E) = src, edges[E..2E) = dst
__global__ void hist_dst(const int* __restrict__ edges, int E, int* __restrict__ counts) {
    int e = blockIdx.x * blockDim.x + threadIdx.x;
    if (e < E) atomicAdd(&counts[edges[E + e]], 1);
}

// in-place: counts_cursor holds counts on entry, exclusive offsets on exit
__global__ void scan_inplace(int* __restrict__ counts_cursor, int N, int* __restrict__ row_ptr) {
    __shared__ int ps[1024];
    int tid = threadIdx.x;
    int chunk = (N + 1023) >> 10;
    int start = min(tid * chunk, N), end = min(start + chunk, N);
    int s = 0;
    for (int i = start; i < end; ++i) s += counts_cursor[i];
    ps[tid] = s;
    __syncthreads();
    if (tid == 0) {
        int run = 0;
        for (int i = 0; i < 1024; ++i) { int t = ps[i]; ps[i] = run; run += t; }
    }
    __syncthreads();
    int off = ps[tid];
    for (int i = start; i < end; ++i) {
        int c = counts_cursor[i];
        row_ptr[i] = off;
        counts_cursor[i] = off;
        off += c;
    }
    if (tid == 1023) row_ptr[N] = off;
}

__global__ void fill_csr(const int* __restrict__ edges, const float* __restrict__ att, int E,
                         int* __restrict__ cursor,
                         int* __restrict__ csr_src, float* __restrict__ csr_att) {
    int e = blockIdx.x * blockDim.x + threadIdx.x;
    if (e < E) {
        int dst = edges[E + e];
        int pos = atomicAdd(&cursor[dst], 1);
        csr_src[pos] = edges[e];
        csr_att[pos] = att[e];
    }
}

// ---------------- fused gather-reduce + blend + clip ------------------------
// 32 lanes per dst row (float4/lane); out = clip(feat0*a + msg*(1-a))
__global__ __launch_bounds__(256) void aggregate_combine(
        const int* __restrict__ row_ptr,
        const int* __restrict__ csr_src, const float* __restrict__ csr_att,
        const float* __restrict__ src_feat,   // other side's cur features
        const float* __restrict__ feat0,      // this side's original x
        const float* __restrict__ alpha_p,
        float* __restrict__ out, int N) {
    int row = blockIdx.x * RPB + (threadIdx.x >> 5);
    int lane = threadIdx.x & 31;
    if (row >= N) return;
    int j = row_ptr[row], end = row_ptr[row + 1];
    float4 acc = make_float4(0.f, 0.f, 0.f, 0.f);
    // 2-edge unroll: two independent gathers in flight
    for (; j + 1 < end; j += 2) {
        int s0 = csr_src[j],     s1 = csr_src[j + 1];
        float a0 = csr_att[j],   a1 = csr_att[j + 1];
        float4 v0 = *reinterpret_cast<const float4*>(src_feat + (size_t)s0 * D + lane * 4);
        float4 v1 = *reinterpret_cast<const float4*>(src_feat + (size_t)s1 * D + lane * 4);
        acc.x += v0.x * a0 + v1.x * a1;
        acc.y += v0.y * a0 + v1.y * a1;
        acc.z += v0.z * a0 + v1.z * a1;
        acc.w += v0.w * a0 + v1.w * a1;
    }
    if (j < end) {
        int s0 = csr_src[j];
        float a0 = csr_att[j];
        float4 v0 = *reinterpret_cast<const float4*>(src_feat + (size_t)s0 * D + lane * 4);
        acc.x += v0.x * a0; acc.y += v0.y * a0; acc.z += v0.z * a0; acc.w += v0.w * a0;
    }
    float al = alpha_p[0], bl = 1.f - al;
    float4 f = *reinterpret_cast<const float4*>(feat0 + (size_t)row * D + lane * 4);
    float4 r;
    r.x = fminf(fmaxf(f.x * al + acc.x * bl, EPSV), CLIP_HI);
    r.y = fminf(fmaxf(f.y * al + acc.y * bl, EPSV), CLIP_HI);
    r.z = fminf(fmaxf(f.z * al + acc.z * bl, EPSV), CLIP_HI);
    r.w = fminf(fmaxf(f.w * al + acc.w * bl, EPSV), CLIP_HI);
    *reinterpret_cast<float4*>(out + (size_t)row * D + lane * 4) = r;
}

// ---------------- fallback (atomic scatter) kernels --------------------------
__global__ void scatter_add(const float* __restrict__ cur, const float* __restrict__ att,
                            const int* __restrict__ edges, int E,
                            float* __restrict__ msg) {
    const long long total = (long long)E * (D / 4);
    long long stride = (long long)gridDim.x * blockDim.x;
    for (long long idx = (long long)blockIdx.x * blockDim.x + threadIdx.x;
         idx < total; idx += stride) {
        int e  = (int)(idx >> 5);
        int ch = (int)(idx & 31);
        int src = edges[e];
        int dst = edges[E + e];
        float a = att[e];
        const float4 v = *reinterpret_cast<const float4*>(cur + (size_t)src * D + ch * 4);
        float* p = msg + (size_t)dst * D + ch * 4;
        atomicAdd(p + 0, v.x * a);
        atomicAdd(p + 1, v.y * a);
        atomicAdd(p + 2, v.z * a);
        atomicAdd(p + 3, v.w * a);
    }
}

__global__ void combine(const float4* __restrict__ feat0, const float4* __restrict__ msg,
                        const float* __restrict__ alpha_p, float4* __restrict__ out, int n4) {
    float a = alpha_p[0];
    float b = 1.f - a;
    int stride = gridDim.x * blockDim.x;
    for (int i = blockIdx.x * blockDim.x + threadIdx.x; i < n4; i += stride) {
        float4 f = feat0[i];
        float4 m = msg[i];
        float4 r;
        r.x = fminf(fmaxf(f.x * a + m.x * b, EPSV), CLIP_HI);
        r.y = fminf(fmaxf(f.y * a + m.y * b, EPSV), CLIP_HI);
        r.z = fminf(fmaxf(f.z * a + m.z * b, EPSV), CLIP_HI);
        r.w = fminf(fmaxf(f.w * a + m.w * b, EPSV), CLIP_HI);
        out[i] = r;
    }
}

extern "C" void kernel_launch(void* const* d_in, const int* in_sizes, int n_in,
                              void* d_out, int out_size, void* d_ws, size_t ws_size,
                              hipStream_t stream) {
    const float* xA    = (const float*)d_in[0];
    const float* xB    = (const float*)d_in[1];
    const float* attAB = (const float*)d_in[2];
    const float* attBA = (const float*)d_in[3];
    const float* fc1_w = (const float*)d_in[4];
    const float* fc1_b = (const float*)d_in[5];
    const float* fc2_w = (const float*)d_in[6];
    const float* fc2_b = (const float*)d_in[7];
    const int*   eAB   = (const int*)d_in[8];   // src in A, dst in B
    const int*   eBA   = (const int*)d_in[9];   // src in B, dst in A

    const int NA = in_sizes[0] / D;
    const int NB = in_sizes[1] / D;
    const int E  = in_sizes[2];

    float* out  = (float*)d_out;
    float* outA = out;                      // [NA, D]
    float* outB = out + (size_t)NA * D;     // [NB, D]

    // ---- ws layout (CSR path) ----
    float* curbuf = (float*)d_ws;                         // (NA+NB)*D
    float* curA   = curbuf;
    float* curB   = curbuf + (size_t)NA * D;
    float* partA  = curbuf + (size_t)(NA + NB) * D;       // G*D
    float* partB  = partA + (size_t)G * D;                // G*D
    float* alpha  = partB + (size_t)G * D;                // pad 4
    int*   row_ptrA = (int*)(alpha + 4);                  // NA+1
    int*   cursorA  = row_ptrA + (NA + 1);                // NA
    int*   row_ptrB = cursorA + NA;                       // NB+1
    int*   cursorB  = row_ptrB + (NB + 1);                // NB
    int*   srcA     = cursorB + NB;                       // E  (edges dst in A, from eBA)
    float* attA_r   = (float*)(srcA + E);                 // E
    int*   srcB     = (int*)(attA_r + E);                 // E  (edges dst in B, from eAB)
    float* attB_r   = (float*)(srcB + E);                 // E
    size_t needed = (size_t)((char*)(attB_r + E) - (char*)d_ws);

    if (ws_size >= needed) {
        // ---------------- CSR path ----------------
        colsum_partial<<<G, D, 0, stream>>>(xA, xB, NA, NB, partA, partB);
        compute_alpha<<<1, D, 0, stream>>>(partA, partB, NA, NB,
                                           fc1_w, fc1_b, fc2_w, fc2_b, alpha);

        hipMemsetAsync(cursorA, 0, (size_t)NA * sizeof(int), stream);
        hipMemsetAsync(cursorB, 0, (size_t)NB * sizeof(int), stream);
        int hb = (E + 255) / 256;
        hist_dst<<<hb, 256, 0, stream>>>(eBA, E, cursorA);
        hist_dst<<<hb, 256, 0, stream>>>(eAB, E, cursorB);
        scan_inplace<<<1, 1024, 0, stream>>>(cursorA, NA, row_ptrA);
        scan_inplace<<<1, 1024, 0, stream>>>(cursorB, NB, row_ptrB);
        fill_csr<<<hb, 256, 0, stream>>>(eBA, attBA, E, cursorA, srcA, attA_r);
        fill_csr<<<hb, 256, 0, stream>>>(eAB, attAB, E, cursorB, srcB, attB_r);

        int gA = (NA + RPB - 1) / RPB;
        int gB = (NB + RPB - 1) / RPB;
        // hop 0: x -> d_out
        aggregate_combine<<<gA, 256, 0, stream>>>(row_ptrA, srcA, attA_r, xB,  xA, alpha, outA, NA);
        aggregate_combine<<<gB, 256, 0, stream>>>(row_ptrB, srcB, attB_r, xA,  xB, alpha, outB, NB);
        // hop 1: d_out -> ws
        aggregate_combine<<<gA, 256, 0, stream>>>(row_ptrA, srcA, attA_r, outB, xA, alpha, curA, NA);
        aggregate_combine<<<gB, 256, 0, stream>>>(row_ptrB, srcB, attB_r, outA, xB, alpha, curB, NB);
        // hop 2: ws -> d_out
        aggregate_combine<<<gA, 256, 0, stream>>>(row_ptrA, srcA, attA_r, curB, xA, alpha, outA, NA);
        aggregate_combine<<<gB, 256, 0, stream>>>(row_ptrB, srcB, attB_r, curA, xB, alpha, outB, NB);
    } else {
        // ---------------- fallback: atomic scatter path ----------------
        float* msgA  = (float*)d_ws;
        float* msgB  = msgA + (size_t)NA * D;
        float* pA    = msgB + (size_t)NB * D;
        float* pB    = pA + (size_t)G * D;
        float* alph  = pB + (size_t)G * D;

        colsum_partial<<<G, D, 0, stream>>>(xA, xB, NA, NB, pA, pB);
        compute_alpha<<<1, D, 0, stream>>>(pA, pB, NA, NB,
                                           fc1_w, fc1_b, fc2_w, fc2_b, alph);

        const size_t msgBytes = ((size_t)NA + (size_t)NB) * D * sizeof(float);
        for (int hop = 0; hop < 3; ++hop) {
            hipMemsetAsync(msgA, 0, msgBytes, stream);
            const float* fA = (hop == 0) ? xA : outA;
            const float* fB = (hop == 0) ? xB : outB;
            scatter_add<<<4096, 256, 0, stream>>>(fB, attBA, eBA, E, msgA);
            scatter_add<<<4096, 256, 0, stream>>>(fA, attAB, eAB, E, msgB);
            combine<<<2048, 256, 0, stream>>>((const float4*)xA, (const float4*)msgA,
                                              alpha, (float4*)outA, NA * D / 4);
            combine<<<2048, 256, 0, stream>>>((const float4*)xB, (const float4*)msgB,
                                              alpha, (float4*)outB, NB * D / 4);
        }
    }
}

// Round 3
// 527.351 us; speedup vs baseline: 12.4834x; 1.4248x over previous
//
#include <hip/hip_runtime.h>
#include <math.h>

#define D 128
#define EPSV 1e-6f
#define CLIP_HI 1e6f
#define G 512          // colsum partial blocks
#define RPB 8          // rows per block in aggregate (256 threads / 32 lanes)
#define SCAN_ELEMS 1024  // elements per scan block (256 thr * 4)

// ---------------- alpha: per-block column partial sums ----------------------
__global__ void colsum_partial(const float* __restrict__ xA, const float* __restrict__ xB,
                               int NA, int NB,
                               float* __restrict__ partA, float* __restrict__ partB) {
    int c = threadIdx.x;   // 0..127 (column)
    int b = blockIdx.x;
    float sa = 0.f, sb = 0.f;
    for (int r = b; r < NA; r += gridDim.x) sa += xA[(size_t)r * D + c];
    for (int r = b; r < NB; r += gridDim.x) sb += xB[(size_t)r * D + c];
    partA[(size_t)b * D + c] = sa;
    partB[(size_t)b * D + c] = sb;
}

// ---------------- alpha: reduce partials + tiny MLP -------------------------
__global__ void compute_alpha(const float* __restrict__ partA, const float* __restrict__ partB,
                              int NA, int NB,
                              const float* __restrict__ fc1_w, const float* __restrict__ fc1_b,
                              const float* __restrict__ fc2_w, const float* __restrict__ fc2_b,
                              float* __restrict__ alpha_out) {
    __shared__ float g[D];
    __shared__ float h[D];
    int c = threadIdx.x;  // 0..127
    float sa = 0.f, sb = 0.f;
    for (int b = 0; b < G; ++b) {
        sa += partA[(size_t)b * D + c];
        sb += partB[(size_t)b * D + c];
    }
    g[c] = 0.5f * (sa / (float)NA + sb / (float)NB);
    __syncthreads();
    float acc = fc1_b[c];
    for (int k = 0; k < D; ++k) acc += g[k] * fc1_w[(size_t)c * D + k];
    h[c] = tanhf(acc);
    __syncthreads();
    if (c == 0) {
        float a = fc2_b[0];
        for (int k = 0; k < D; ++k) a += h[k] * fc2_w[k];
        a = 1.f / (1.f + expf(-a));
        a = fminf(fmaxf(a, EPSV), 1.f - EPSV);
        *alpha_out = a;
    }
}

// ---------------- CSR build --------------------------------------------------
// edge layout: edges[0..E) = src, edges[E..2E) = dst
// fused histogram for both directions
__global__ void hist_dst2(const int* __restrict__ eA, int E, int* __restrict__ countsA,
                          const int* __restrict__ eB, int* __restrict__ countsB) {
    int t = blockIdx.x * blockDim.x + threadIdx.x;
    if (t < E) {
        atomicAdd(&countsA[eA[E + t]], 1);
    } else {
        int e = t - E;
        if (e < E) atomicAdd(&countsB[eB[E + e]], 1);
    }
}

// ---- 3-phase parallel exclusive scan over two arrays (A then B blocks) -----
// phase 1: per-block sums
__global__ void scan_p1(const int* __restrict__ cA, int NAe, int nbA, int* __restrict__ bsA,
                        const int* __restrict__ cB, int NBe, int* __restrict__ bsB) {
    const int* c; int N; int* bs; int b;
    if ((int)blockIdx.x < nbA) { c = cA; N = NAe; bs = bsA; b = blockIdx.x; }
    else                       { c = cB; N = NBe; bs = bsB; b = blockIdx.x - nbA; }
    __shared__ int red[256];
    int tid = threadIdx.x;
    int base = b * SCAN_ELEMS + tid * 4;
    int s = 0;
    #pragma unroll
    for (int i = 0; i < 4; ++i) { int idx = base + i; if (idx < N) s += c[idx]; }
    red[tid] = s;
    __syncthreads();
    for (int off = 128; off > 0; off >>= 1) {
        if (tid < off) red[tid] += red[tid + off];
        __syncthreads();
    }
    if (tid == 0) bs[b] = red[0];
}

// phase 2: exclusive-scan the (<=64) block sums; block 0 -> A, block 1 -> B
__global__ void scan_p2(int* __restrict__ bsA, int nbA, int* __restrict__ rpA, int NAe,
                        int* __restrict__ bsB, int nbB, int* __restrict__ rpB, int NBe) {
    int* bs; int nb; int* rp; int N;
    if (blockIdx.x == 0) { bs = bsA; nb = nbA; rp = rpA; N = NAe; }
    else                 { bs = bsB; nb = nbB; rp = rpB; N = NBe; }
    if (threadIdx.x == 0) {
        int run = 0;
        for (int i = 0; i < nb; ++i) { int t = bs[i]; bs[i] = run; run += t; }
        rp[N] = run;
    }
}

// phase 3: per-block rescan + write row_ptr and cursor (in-place over counts)
__global__ void scan_p3(int* __restrict__ cA, int NAe, const int* __restrict__ bsA, int nbA,
                        int* __restrict__ rpA,
                        int* __restrict__ cB, int NBe, const int* __restrict__ bsB,
                        int* __restrict__ rpB) {
    int* c; int N; const int* bs; int* rp; int b;
    if ((int)blockIdx.x < nbA) { c = cA; N = NAe; bs = bsA; rp = rpA; b = blockIdx.x; }
    else                       { c = cB; N = NBe; bs = bsB; rp = rpB; b = blockIdx.x - nbA; }
    __shared__ int sh[256];
    int tid = threadIdx.x;
    int base = b * SCAN_ELEMS + tid * 4;
    int v[4]; int s = 0;
    #pragma unroll
    for (int i = 0; i < 4; ++i) { int idx = base + i; v[i] = (idx < N) ? c[idx] : 0; s += v[i]; }
    sh[tid] = s;
    __syncthreads();
    // Hillis-Steele inclusive scan of per-thread sums
    for (int off = 1; off < 256; off <<= 1) {
        int t = (tid >= off) ? sh[tid - off] : 0;
        __syncthreads();
        sh[tid] += t;
        __syncthreads();
    }
    int excl = bs[b] + sh[tid] - s;
    #pragma unroll
    for (int i = 0; i < 4; ++i) {
        int idx = base + i;
        if (idx < N) { rp[idx] = excl; c[idx] = excl; excl += v[i]; }  // c becomes cursor
    }
}

// fused CSR fill for both directions
__global__ void fill_csr2(const int* __restrict__ eA, const float* __restrict__ attA, int E,
                          int* __restrict__ curA, int* __restrict__ sA, float* __restrict__ aA,
                          const int* __restrict__ eB, const float* __restrict__ attB,
                          int* __restrict__ curB, int* __restrict__ sB, float* __restrict__ aB) {
    int t = blockIdx.x * blockDim.x + threadIdx.x;
    if (t < E) {
        int dst = eA[E + t];
        int pos = atomicAdd(&curA[dst], 1);
        sA[pos] = eA[t];
        aA[pos] = attA[t];
    } else {
        int e = t - E;
        if (e < E) {
            int dst = eB[E + e];
            int pos = atomicAdd(&curB[dst], 1);
            sB[pos] = eB[e];
            aB[pos] = attB[e];
        }
    }
}

// ---------------- fused gather-reduce + blend + clip ------------------------
// 32 lanes per dst row (float4/lane); out = clip(feat0*a + msg*(1-a))
__global__ __launch_bounds__(256) void aggregate_combine(
        const int* __restrict__ row_ptr,
        const int* __restrict__ csr_src, const float* __restrict__ csr_att,
        const float* __restrict__ src_feat,   // other side's cur features
        const float* __restrict__ feat0,      // this side's original x
        const float* __restrict__ alpha_p,
        float* __restrict__ out, int N) {
    int row = blockIdx.x * RPB + (threadIdx.x >> 5);
    int lane = threadIdx.x & 31;
    if (row >= N) return;
    int j = row_ptr[row], end = row_ptr[row + 1];
    float4 acc = make_float4(0.f, 0.f, 0.f, 0.f);
    for (; j + 1 < end; j += 2) {
        int s0 = csr_src[j],     s1 = csr_src[j + 1];
        float a0 = csr_att[j],   a1 = csr_att[j + 1];
        float4 v0 = *reinterpret_cast<const float4*>(src_feat + (size_t)s0 * D + lane * 4);
        float4 v1 = *reinterpret_cast<const float4*>(src_feat + (size_t)s1 * D + lane * 4);
        acc.x += v0.x * a0 + v1.x * a1;
        acc.y += v0.y * a0 + v1.y * a1;
        acc.z += v0.z * a0 + v1.z * a1;
        acc.w += v0.w * a0 + v1.w * a1;
    }
    if (j < end) {
        int s0 = csr_src[j];
        float a0 = csr_att[j];
        float4 v0 = *reinterpret_cast<const float4*>(src_feat + (size_t)s0 * D + lane * 4);
        acc.x += v0.x * a0; acc.y += v0.y * a0; acc.z += v0.z * a0; acc.w += v0.w * a0;
    }
    float al = alpha_p[0], bl = 1.f - al;
    float4 f = *reinterpret_cast<const float4*>(feat0 + (size_t)row * D + lane * 4);
    float4 r;
    r.x = fminf(fmaxf(f.x * al + acc.x * bl, EPSV), CLIP_HI);
    r.y = fminf(fmaxf(f.y * al + acc.y * bl, EPSV), CLIP_HI);
    r.z = fminf(fmaxf(f.z * al + acc.z * bl, EPSV), CLIP_HI);
    r.w = fminf(fmaxf(f.w * al + acc.w * bl, EPSV), CLIP_HI);
    *reinterpret_cast<float4*>(out + (size_t)row * D + lane * 4) = r;
}

// ---------------- fallback (atomic scatter) kernels --------------------------
__global__ void scatter_add(const float* __restrict__ cur, const float* __restrict__ att,
                            const int* __restrict__ edges, int E,
                            float* __restrict__ msg) {
    const long long total = (long long)E * (D / 4);
    long long stride = (long long)gridDim.x * blockDim.x;
    for (long long idx = (long long)blockIdx.x * blockDim.x + threadIdx.x;
         idx < total; idx += stride) {
        int e  = (int)(idx >> 5);
        int ch = (int)(idx & 31);
        int src = edges[e];
        int dst = edges[E + e];
        float a = att[e];
        const float4 v = *reinterpret_cast<const float4*>(cur + (size_t)src * D + ch * 4);
        float* p = msg + (size_t)dst * D + ch * 4;
        atomicAdd(p + 0, v.x * a);
        atomicAdd(p + 1, v.y * a);
        atomicAdd(p + 2, v.z * a);
        atomicAdd(p + 3, v.w * a);
    }
}

__global__ void combine(const float4* __restrict__ feat0, const float4* __restrict__ msg,
                        const float* __restrict__ alpha_p, float4* __restrict__ out, int n4) {
    float a = alpha_p[0];
    float b = 1.f - a;
    int stride = gridDim.x * blockDim.x;
    for (int i = blockIdx.x * blockDim.x + threadIdx.x; i < n4; i += stride) {
        float4 f = feat0[i];
        float4 m = msg[i];
        float4 r;
        r.x = fminf(fmaxf(f.x * a + m.x * b, EPSV), CLIP_HI);
        r.y = fminf(fmaxf(f.y * a + m.y * b, EPSV), CLIP_HI);
        r.z = fminf(fmaxf(f.z * a + m.z * b, EPSV), CLIP_HI);
        r.w = fminf(fmaxf(f.w * a + m.w * b, EPSV), CLIP_HI);
        out[i] = r;
    }
}

extern "C" void kernel_launch(void* const* d_in, const int* in_sizes, int n_in,
                              void* d_out, int out_size, void* d_ws, size_t ws_size,
                              hipStream_t stream) {
    const float* xA    = (const float*)d_in[0];
    const float* xB    = (const float*)d_in[1];
    const float* attAB = (const float*)d_in[2];
    const float* attBA = (const float*)d_in[3];
    const float* fc1_w = (const float*)d_in[4];
    const float* fc1_b = (const float*)d_in[5];
    const float* fc2_w = (const float*)d_in[6];
    const float* fc2_b = (const float*)d_in[7];
    const int*   eAB   = (const int*)d_in[8];   // src in A, dst in B
    const int*   eBA   = (const int*)d_in[9];   // src in B, dst in A

    const int NA = in_sizes[0] / D;
    const int NB = in_sizes[1] / D;
    const int E  = in_sizes[2];

    float* out  = (float*)d_out;
    float* outA = out;                      // [NA, D]
    float* outB = out + (size_t)NA * D;     // [NB, D]

    // ---- ws layout (CSR path) ----
    float* curbuf = (float*)d_ws;                         // (NA+NB)*D
    float* curA   = curbuf;
    float* curB   = curbuf + (size_t)NA * D;
    float* partA  = curbuf + (size_t)(NA + NB) * D;       // G*D
    float* partB  = partA + (size_t)G * D;                // G*D
    float* alpha  = partB + (size_t)G * D;                // pad 4
    int*   row_ptrA = (int*)(alpha + 4);                  // NA+1
    int*   cursorA  = row_ptrA + (NA + 1);                // NA (counts -> offsets -> cursor)
    int*   row_ptrB = cursorA + NA;                       // NB+1
    int*   cursorB  = row_ptrB + (NB + 1);                // NB
    int*   srcA     = cursorB + NB;                       // E  (edges dst in A, from eBA)
    float* attA_r   = (float*)(srcA + E);                 // E
    int*   srcB     = (int*)(attA_r + E);                 // E  (edges dst in B, from eAB)
    float* attB_r   = (float*)(srcB + E);                 // E
    int*   bsA      = (int*)(attB_r + E);                 // 64 block sums
    int*   bsB      = bsA + 64;                           // 64
    size_t needed = (size_t)((char*)(bsB + 64) - (char*)d_ws);

    if (ws_size >= needed) {
        // ---------------- CSR path ----------------
        colsum_partial<<<G, D, 0, stream>>>(xA, xB, NA, NB, partA, partB);
        compute_alpha<<<1, D, 0, stream>>>(partA, partB, NA, NB,
                                           fc1_w, fc1_b, fc2_w, fc2_b, alpha);

        hipMemsetAsync(cursorA, 0, (size_t)NA * sizeof(int), stream);
        hipMemsetAsync(cursorB, 0, (size_t)NB * sizeof(int), stream);
        int hb2 = (2 * E + 255) / 256;
        hist_dst2<<<hb2, 256, 0, stream>>>(eBA, E, cursorA, eAB, cursorB);

        int nbA = (NA + SCAN_ELEMS - 1) / SCAN_ELEMS;
        int nbB = (NB + SCAN_ELEMS - 1) / SCAN_ELEMS;
        scan_p1<<<nbA + nbB, 256, 0, stream>>>(cursorA, NA, nbA, bsA, cursorB, NB, bsB);
        scan_p2<<<2, 64, 0, stream>>>(bsA, nbA, row_ptrA, NA, bsB, nbB, row_ptrB, NB);
        scan_p3<<<nbA + nbB, 256, 0, stream>>>(cursorA, NA, bsA, nbA, row_ptrA,
                                               cursorB, NB, bsB, row_ptrB);

        fill_csr2<<<hb2, 256, 0, stream>>>(eBA, attBA, E, cursorA, srcA, attA_r,
                                           eAB, attAB, cursorB, srcB, attB_r);

        int gA = (NA + RPB - 1) / RPB;
        int gB = (NB + RPB - 1) / RPB;
        // hop 0: x -> d_out
        aggregate_combine<<<gA, 256, 0, stream>>>(row_ptrA, srcA, attA_r, xB,  xA, alpha, outA, NA);
        aggregate_combine<<<gB, 256, 0, stream>>>(row_ptrB, srcB, attB_r, xA,  xB, alpha, outB, NB);
        // hop 1: d_out -> ws
        aggregate_combine<<<gA, 256, 0, stream>>>(row_ptrA, srcA, attA_r, outB, xA, alpha, curA, NA);
        aggregate_combine<<<gB, 256, 0, stream>>>(row_ptrB, srcB, attB_r, outA, xB, alpha, curB, NB);
        // hop 2: ws -> d_out
        aggregate_combine<<<gA, 256, 0, stream>>>(row_ptrA, srcA, attA_r, curB, xA, alpha, outA, NA);
        aggregate_combine<<<gB, 256, 0, stream>>>(row_ptrB, srcB, attB_r, curA, xB, alpha, outB, NB);
    } else {
        // ---------------- fallback: atomic scatter path ----------------
        float* msgA  = (float*)d_ws;
        float* msgB  = msgA + (size_t)NA * D;
        float* pA    = msgB + (size_t)NB * D;
        float* pB    = pA + (size_t)G * D;
        float* alph  = pB + (size_t)G * D;

        colsum_partial<<<G, D, 0, stream>>>(xA, xB, NA, NB, pA, pB);
        compute_alpha<<<1, D, 0, stream>>>(pA, pB, NA, NB,
                                           fc1_w, fc1_b, fc2_w, fc2_b, alph);

        const size_t msgBytes = ((size_t)NA + (size_t)NB) * D * sizeof(float);
        for (int hop = 0; hop < 3; ++hop) {
            hipMemsetAsync(msgA, 0, msgBytes, stream);
            const float* fA = (hop == 0) ? xA : outA;
            const float* fB = (hop == 0) ? xB : outB;
            scatter_add<<<4096, 256, 0, stream>>>(fB, attBA, eBA, E, msgA);
            scatter_add<<<4096, 256, 0, stream>>>(fA, attAB, eAB, E, msgB);
            combine<<<2048, 256, 0, stream>>>((const float4*)xA, (const float4*)msgA,
                                              alph, (float4*)outA, NA * D / 4);
            combine<<<2048, 256, 0, stream>>>((const float4*)xB, (const float4*)msgB,
                                              alph, (float4*)outB, NB * D / 4);
        }
    }
}

// Round 4
// 411.962 us; speedup vs baseline: 15.9800x; 1.2801x over previous
//
#include <hip/hip_runtime.h>
#include <math.h>

#define D 128
#define EPSV 1e-6f
#define CLIP_HI 1e6f
#define G 512            // colsum partial blocks
#define RPB 8            // rows per block in aggregate (256 threads / 32 lanes)
#define SCAN_ELEMS 1024  // elements per scan block (256 thr * 4)

// ---------------- bf16 helpers ----------------------------------------------
__device__ __forceinline__ float bf2f(unsigned short u) {
    return __uint_as_float(((unsigned)u) << 16);
}
__device__ __forceinline__ unsigned short f2bf(float f) {
    unsigned u = __float_as_uint(f);
    u = u + 0x7FFFu + ((u >> 16) & 1u);   // round-to-nearest-even
    return (unsigned short)(u >> 16);
}

// ---------------- alpha: per-block column partial sums (vectorized) ---------
__global__ __launch_bounds__(256) void colsum_partial(
        const float* __restrict__ xA, const float* __restrict__ xB,
        int NA, int NB, float* __restrict__ partA, float* __restrict__ partB) {
    __shared__ float4 sh[256];
    int tid = threadIdx.x;
    int c4  = tid & 31;   // float4 column chunk
    int rs  = tid >> 5;   // 0..7 row sub-slot
    float4 sa = make_float4(0.f, 0.f, 0.f, 0.f);
    float4 sb = make_float4(0.f, 0.f, 0.f, 0.f);
    for (int r = blockIdx.x * 8 + rs; r < NA; r += gridDim.x * 8) {
        float4 v = *reinterpret_cast<const float4*>(xA + (size_t)r * D + c4 * 4);
        sa.x += v.x; sa.y += v.y; sa.z += v.z; sa.w += v.w;
    }
    for (int r = blockIdx.x * 8 + rs; r < NB; r += gridDim.x * 8) {
        float4 v = *reinterpret_cast<const float4*>(xB + (size_t)r * D + c4 * 4);
        sb.x += v.x; sb.y += v.y; sb.z += v.z; sb.w += v.w;
    }
    // reduce A over rs
    sh[tid] = sa; __syncthreads();
    if (tid < 128) { sh[tid].x += sh[tid+128].x; sh[tid].y += sh[tid+128].y; sh[tid].z += sh[tid+128].z; sh[tid].w += sh[tid+128].w; } __syncthreads();
    if (tid < 64)  { sh[tid].x += sh[tid+64].x;  sh[tid].y += sh[tid+64].y;  sh[tid].z += sh[tid+64].z;  sh[tid].w += sh[tid+64].w;  } __syncthreads();
    if (tid < 32)  {
        float4 t = sh[tid]; float4 u = sh[tid+32];
        t.x += u.x; t.y += u.y; t.z += u.z; t.w += u.w;
        *reinterpret_cast<float4*>(partA + (size_t)blockIdx.x * D + tid * 4) = t;
    }
    __syncthreads();
    // reduce B over rs
    sh[tid] = sb; __syncthreads();
    if (tid < 128) { sh[tid].x += sh[tid+128].x; sh[tid].y += sh[tid+128].y; sh[tid].z += sh[tid+128].z; sh[tid].w += sh[tid+128].w; } __syncthreads();
    if (tid < 64)  { sh[tid].x += sh[tid+64].x;  sh[tid].y += sh[tid+64].y;  sh[tid].z += sh[tid+64].z;  sh[tid].w += sh[tid+64].w;  } __syncthreads();
    if (tid < 32)  {
        float4 t = sh[tid]; float4 u = sh[tid+32];
        t.x += u.x; t.y += u.y; t.z += u.z; t.w += u.w;
        *reinterpret_cast<float4*>(partB + (size_t)blockIdx.x * D + tid * 4) = t;
    }
}

// ---------------- alpha: reduce partials + tiny MLP -------------------------
__global__ void compute_alpha(const float* __restrict__ partA, const float* __restrict__ partB,
                              int NA, int NB,
                              const float* __restrict__ fc1_w, const float* __restrict__ fc1_b,
                              const float* __restrict__ fc2_w, const float* __restrict__ fc2_b,
                              float* __restrict__ alpha_out) {
    __shared__ float g[D];
    __shared__ float h[D];
    int c = threadIdx.x;  // 0..127
    float sa = 0.f, sb = 0.f;
    for (int b = 0; b < G; ++b) {
        sa += partA[(size_t)b * D + c];
        sb += partB[(size_t)b * D + c];
    }
    g[c] = 0.5f * (sa / (float)NA + sb / (float)NB);
    __syncthreads();
    float acc = fc1_b[c];
    for (int k = 0; k < D; ++k) acc += g[k] * fc1_w[(size_t)c * D + k];
    h[c] = tanhf(acc);
    __syncthreads();
    if (c == 0) {
        float a = fc2_b[0];
        for (int k = 0; k < D; ++k) a += h[k] * fc2_w[k];
        a = 1.f / (1.f + expf(-a));
        a = fminf(fmaxf(a, EPSV), 1.f - EPSV);
        *alpha_out = a;
    }
}

// ---------------- x -> bf16 tables ------------------------------------------
__global__ void to_bf16_2(const float4* __restrict__ inA, ushort4* __restrict__ outA, long nA4,
                          const float4* __restrict__ inB, ushort4* __restrict__ outB, long nB4) {
    long stride = (long)gridDim.x * blockDim.x;
    long total = nA4 + nB4;
    for (long i = (long)blockIdx.x * blockDim.x + threadIdx.x; i < total; i += stride) {
        const float4* in; ushort4* out; long idx;
        if (i < nA4) { in = inA; out = outA; idx = i; }
        else         { in = inB; out = outB; idx = i - nA4; }
        float4 v = in[idx];
        ushort4 o;
        o.x = f2bf(v.x); o.y = f2bf(v.y); o.z = f2bf(v.z); o.w = f2bf(v.w);
        out[idx] = o;
    }
}

// ---------------- CSR build --------------------------------------------------
// edge layout: edges[0..E) = src, edges[E..2E) = dst
__global__ void hist_dst2(const int* __restrict__ eA, int E, int* __restrict__ countsA,
                          const int* __restrict__ eB, int* __restrict__ countsB) {
    int t = blockIdx.x * blockDim.x + threadIdx.x;
    if (t < E) {
        atomicAdd(&countsA[eA[E + t]], 1);
    } else {
        int e = t - E;
        if (e < E) atomicAdd(&countsB[eB[E + e]], 1);
    }
}

// ---- 3-phase parallel exclusive scan over two arrays (A then B blocks) -----
__global__ void scan_p1(const int* __restrict__ cA, int NAe, int nbA, int* __restrict__ bsA,
                        const int* __restrict__ cB, int NBe, int* __restrict__ bsB) {
    const int* c; int N; int* bs; int b;
    if ((int)blockIdx.x < nbA) { c = cA; N = NAe; bs = bsA; b = blockIdx.x; }
    else                       { c = cB; N = NBe; bs = bsB; b = blockIdx.x - nbA; }
    __shared__ int red[256];
    int tid = threadIdx.x;
    int base = b * SCAN_ELEMS + tid * 4;
    int s = 0;
    #pragma unroll
    for (int i = 0; i < 4; ++i) { int idx = base + i; if (idx < N) s += c[idx]; }
    red[tid] = s;
    __syncthreads();
    for (int off = 128; off > 0; off >>= 1) {
        if (tid < off) red[tid] += red[tid + off];
        __syncthreads();
    }
    if (tid == 0) bs[b] = red[0];
}

__global__ void scan_p2(int* __restrict__ bsA, int nbA, int* __restrict__ rpA, int NAe,
                        int* __restrict__ bsB, int nbB, int* __restrict__ rpB, int NBe) {
    int* bs; int nb; int* rp; int N;
    if (blockIdx.x == 0) { bs = bsA; nb = nbA; rp = rpA; N = NAe; }
    else                 { bs = bsB; nb = nbB; rp = rpB; N = NBe; }
    if (threadIdx.x == 0) {
        int run = 0;
        for (int i = 0; i < nb; ++i) { int t = bs[i]; bs[i] = run; run += t; }
        rp[N] = run;
    }
}

__global__ void scan_p3(int* __restrict__ cA, int NAe, const int* __restrict__ bsA, int nbA,
                        int* __restrict__ rpA,
                        int* __restrict__ cB, int NBe, const int* __restrict__ bsB,
                        int* __restrict__ rpB) {
    int* c; int N; const int* bs; int* rp; int b;
    if ((int)blockIdx.x < nbA) { c = cA; N = NAe; bs = bsA; rp = rpA; b = blockIdx.x; }
    else                       { c = cB; N = NBe; bs = bsB; rp = rpB; b = blockIdx.x - nbA; }
    __shared__ int sh[256];
    int tid = threadIdx.x;
    int base = b * SCAN_ELEMS + tid * 4;
    int v[4]; int s = 0;
    #pragma unroll
    for (int i = 0; i < 4; ++i) { int idx = base + i; v[i] = (idx < N) ? c[idx] : 0; s += v[i]; }
    sh[tid] = s;
    __syncthreads();
    for (int off = 1; off < 256; off <<= 1) {
        int t = (tid >= off) ? sh[tid - off] : 0;
        __syncthreads();
        sh[tid] += t;
        __syncthreads();
    }
    int excl = bs[b] + sh[tid] - s;
    #pragma unroll
    for (int i = 0; i < 4; ++i) {
        int idx = base + i;
        if (idx < N) { rp[idx] = excl; c[idx] = excl; excl += v[i]; }  // c becomes cursor
    }
}

// fused CSR fill: packed (src, att) int2 -> one 8B scattered write per edge
__global__ void fill_csr2(const int* __restrict__ eA, const float* __restrict__ attA, int E,
                          int* __restrict__ curA, int2* __restrict__ csrA,
                          const int* __restrict__ eB, const float* __restrict__ attB,
                          int* __restrict__ curB, int2* __restrict__ csrB) {
    int t = blockIdx.x * blockDim.x + threadIdx.x;
    if (t < E) {
        int dst = eA[E + t];
        int pos = atomicAdd(&curA[dst], 1);
        int2 v; v.x = eA[t]; v.y = __float_as_int(attA[t]);
        csrA[pos] = v;
    } else {
        int e = t - E;
        if (e < E) {
            int dst = eB[E + e];
            int pos = atomicAdd(&curB[dst], 1);
            int2 v; v.x = eB[e]; v.y = __float_as_int(attB[e]);
            csrB[pos] = v;
        }
    }
}

// ---------------- fused gather-reduce + blend + clip ------------------------
// 32 lanes per dst row; bf16 gathers, fp32 accumulate.
// LAST=0: write bf16 table for next hop. LAST=1: write fp32 d_out.
template <int LAST>
__global__ __launch_bounds__(256) void aggregate_combine(
        const int* __restrict__ row_ptr, const int2* __restrict__ csr,
        const unsigned short* __restrict__ src_feat,  // other side's cur (bf16)
        const float* __restrict__ feat0,              // this side's original x (fp32)
        const float* __restrict__ alpha_p,
        unsigned short* __restrict__ out_bf, float* __restrict__ out_f32, int N) {
    int row = blockIdx.x * RPB + (threadIdx.x >> 5);
    int lane = threadIdx.x & 31;
    if (row >= N) return;
    int j = row_ptr[row], end = row_ptr[row + 1];
    float4 acc = make_float4(0.f, 0.f, 0.f, 0.f);
    for (; j + 1 < end; j += 2) {
        int2 c0 = csr[j], c1 = csr[j + 1];
        ushort4 v0 = *reinterpret_cast<const ushort4*>(src_feat + (size_t)c0.x * D + lane * 4);
        ushort4 v1 = *reinterpret_cast<const ushort4*>(src_feat + (size_t)c1.x * D + lane * 4);
        float a0 = __int_as_float(c0.y), a1 = __int_as_float(c1.y);
        acc.x += bf2f(v0.x) * a0 + bf2f(v1.x) * a1;
        acc.y += bf2f(v0.y) * a0 + bf2f(v1.y) * a1;
        acc.z += bf2f(v0.z) * a0 + bf2f(v1.z) * a1;
        acc.w += bf2f(v0.w) * a0 + bf2f(v1.w) * a1;
    }
    if (j < end) {
        int2 c0 = csr[j];
        ushort4 v0 = *reinterpret_cast<const ushort4*>(src_feat + (size_t)c0.x * D + lane * 4);
        float a0 = __int_as_float(c0.y);
        acc.x += bf2f(v0.x) * a0;
        acc.y += bf2f(v0.y) * a0;
        acc.z += bf2f(v0.z) * a0;
        acc.w += bf2f(v0.w) * a0;
    }
    float al = alpha_p[0], bl = 1.f - al;
    float4 f = *reinterpret_cast<const float4*>(feat0 + (size_t)row * D + lane * 4);
    float4 r;
    r.x = fminf(fmaxf(f.x * al + acc.x * bl, EPSV), CLIP_HI);
    r.y = fminf(fmaxf(f.y * al + acc.y * bl, EPSV), CLIP_HI);
    r.z = fminf(fmaxf(f.z * al + acc.z * bl, EPSV), CLIP_HI);
    r.w = fminf(fmaxf(f.w * al + acc.w * bl, EPSV), CLIP_HI);
    if (LAST) {
        *reinterpret_cast<float4*>(out_f32 + (size_t)row * D + lane * 4) = r;
    } else {
        ushort4 o;
        o.x = f2bf(r.x); o.y = f2bf(r.y); o.z = f2bf(r.z); o.w = f2bf(r.w);
        *reinterpret_cast<ushort4*>(out_bf + (size_t)row * D + lane * 4) = o;
    }
}

// ---------------- fallback (atomic scatter) kernels --------------------------
__global__ void scatter_add(const float* __restrict__ cur, const float* __restrict__ att,
                            const int* __restrict__ edges, int E,
                            float* __restrict__ msg) {
    const long long total = (long long)E * (D / 4);
    long long stride = (long long)gridDim.x * blockDim.x;
    for (long long idx = (long long)blockIdx.x * blockDim.x + threadIdx.x;
         idx < total; idx += stride) {
        int e  = (int)(idx >> 5);
        int ch = (int)(idx & 31);
        int src = edges[e];
        int dst = edges[E + e];
        float a = att[e];
        const float4 v = *reinterpret_cast<const float4*>(cur + (size_t)src * D + ch * 4);
        float* p = msg + (size_t)dst * D + ch * 4;
        atomicAdd(p + 0, v.x * a);
        atomicAdd(p + 1, v.y * a);
        atomicAdd(p + 2, v.z * a);
        atomicAdd(p + 3, v.w * a);
    }
}

__global__ void combine(const float4* __restrict__ feat0, const float4* __restrict__ msg,
                        const float* __restrict__ alpha_p, float4* __restrict__ out, int n4) {
    float a = alpha_p[0];
    float b = 1.f - a;
    int stride = gridDim.x * blockDim.x;
    for (int i = blockIdx.x * blockDim.x + threadIdx.x; i < n4; i += stride) {
        float4 f = feat0[i];
        float4 m = msg[i];
        float4 r;
        r.x = fminf(fmaxf(f.x * a + m.x * b, EPSV), CLIP_HI);
        r.y = fminf(fmaxf(f.y * a + m.y * b, EPSV), CLIP_HI);
        r.z = fminf(fmaxf(f.z * a + m.z * b, EPSV), CLIP_HI);
        r.w = fminf(fmaxf(f.w * a + m.w * b, EPSV), CLIP_HI);
        out[i] = r;
    }
}

extern "C" void kernel_launch(void* const* d_in, const int* in_sizes, int n_in,
                              void* d_out, int out_size, void* d_ws, size_t ws_size,
                              hipStream_t stream) {
    const float* xA    = (const float*)d_in[0];
    const float* xB    = (const float*)d_in[1];
    const float* attAB = (const float*)d_in[2];
    const float* attBA = (const float*)d_in[3];
    const float* fc1_w = (const float*)d_in[4];
    const float* fc1_b = (const float*)d_in[5];
    const float* fc2_w = (const float*)d_in[6];
    const float* fc2_b = (const float*)d_in[7];
    const int*   eAB   = (const int*)d_in[8];   // src in A, dst in B
    const int*   eBA   = (const int*)d_in[9];   // src in B, dst in A

    const int NA = in_sizes[0] / D;
    const int NB = in_sizes[1] / D;
    const int E  = in_sizes[2];

    float* out  = (float*)d_out;
    float* outA = out;                      // [NA, D]
    float* outB = out + (size_t)NA * D;     // [NB, D]

    // ---- ws layout (CSR + bf16-table path) ----
    unsigned short* tbl0 = (unsigned short*)d_ws;               // (NA+NB)*D bf16
    unsigned short* tbl1 = tbl0 + (size_t)(NA + NB) * D;        // (NA+NB)*D bf16
    int2*  csrA   = (int2*)(tbl1 + (size_t)(NA + NB) * D);      // E
    int2*  csrB   = csrA + E;                                   // E
    float* partA  = (float*)(csrB + E);                         // G*D
    float* partB  = partA + (size_t)G * D;                      // G*D
    float* alpha  = partB + (size_t)G * D;                      // pad 4
    int*   row_ptrA = (int*)(alpha + 4);                        // NA+1
    int*   cursorA  = row_ptrA + (NA + 1);                      // NA
    int*   row_ptrB = cursorA + NA;                             // NB+1
    int*   cursorB  = row_ptrB + (NB + 1);                      // NB
    int*   bsA      = cursorB + NB;                             // 64
    int*   bsB      = bsA + 64;                                 // 64
    size_t needed = (size_t)((char*)(bsB + 64) - (char*)d_ws);

    unsigned short* tbl0A = tbl0;
    unsigned short* tbl0B = tbl0 + (size_t)NA * D;
    unsigned short* tbl1A = tbl1;
    unsigned short* tbl1B = tbl1 + (size_t)NA * D;

    if (ws_size >= needed) {
        // ---------------- CSR path ----------------
        colsum_partial<<<G, 256, 0, stream>>>(xA, xB, NA, NB, partA, partB);
        compute_alpha<<<1, D, 0, stream>>>(partA, partB, NA, NB,
                                           fc1_w, fc1_b, fc2_w, fc2_b, alpha);

        // x -> bf16 tables
        long nA4 = (long)NA * (D / 4), nB4 = (long)NB * (D / 4);
        to_bf16_2<<<2048, 256, 0, stream>>>((const float4*)xA, (ushort4*)tbl0A, nA4,
                                            (const float4*)xB, (ushort4*)tbl0B, nB4);

        hipMemsetAsync(cursorA, 0, (size_t)NA * sizeof(int), stream);
        hipMemsetAsync(cursorB, 0, (size_t)NB * sizeof(int), stream);
        int hb2 = (2 * E + 255) / 256;
        hist_dst2<<<hb2, 256, 0, stream>>>(eBA, E, cursorA, eAB, cursorB);

        int nbA = (NA + SCAN_ELEMS - 1) / SCAN_ELEMS;
        int nbB = (NB + SCAN_ELEMS - 1) / SCAN_ELEMS;
        scan_p1<<<nbA + nbB, 256, 0, stream>>>(cursorA, NA, nbA, bsA, cursorB, NB, bsB);
        scan_p2<<<2, 64, 0, stream>>>(bsA, nbA, row_ptrA, NA, bsB, nbB, row_ptrB, NB);
        scan_p3<<<nbA + nbB, 256, 0, stream>>>(cursorA, NA, bsA, nbA, row_ptrA,
                                               cursorB, NB, bsB, row_ptrB);

        fill_csr2<<<hb2, 256, 0, stream>>>(eBA, attBA, E, cursorA, csrA,
                                           eAB, attAB, cursorB, csrB);

        int gA = (NA + RPB - 1) / RPB;
        int gB = (NB + RPB - 1) / RPB;
        // hop 0: tbl0 (x) -> tbl1
        aggregate_combine<0><<<gA, 256, 0, stream>>>(row_ptrA, csrA, tbl0B, xA, alpha, tbl1A, nullptr, NA);
        aggregate_combine<0><<<gB, 256, 0, stream>>>(row_ptrB, csrB, tbl0A, xB, alpha, tbl1B, nullptr, NB);
        // hop 1: tbl1 -> tbl0
        aggregate_combine<0><<<gA, 256, 0, stream>>>(row_ptrA, csrA, tbl1B, xA, alpha, tbl0A, nullptr, NA);
        aggregate_combine<0><<<gB, 256, 0, stream>>>(row_ptrB, csrB, tbl1A, xB, alpha, tbl0B, nullptr, NB);
        // hop 2: tbl0 -> d_out (fp32)
        aggregate_combine<1><<<gA, 256, 0, stream>>>(row_ptrA, csrA, tbl0B, xA, alpha, nullptr, outA, NA);
        aggregate_combine<1><<<gB, 256, 0, stream>>>(row_ptrB, csrB, tbl0A, xB, alpha, nullptr, outB, NB);
    } else {
        // ---------------- fallback: atomic scatter path ----------------
        float* msgA  = (float*)d_ws;
        float* msgB  = msgA + (size_t)NA * D;
        float* pA    = msgB + (size_t)NB * D;
        float* pB    = pA + (size_t)G * D;
        float* alph  = pB + (size_t)G * D;

        colsum_partial<<<G, 256, 0, stream>>>(xA, xB, NA, NB, pA, pB);
        compute_alpha<<<1, D, 0, stream>>>(pA, pB, NA, NB,
                                           fc1_w, fc1_b, fc2_w, fc2_b, alph);

        const size_t msgBytes = ((size_t)NA + (size_t)NB) * D * sizeof(float);
        for (int hop = 0; hop < 3; ++hop) {
            hipMemsetAsync(msgA, 0, msgBytes, stream);
            const float* fA = (hop == 0) ? xA : outA;
            const float* fB = (hop == 0) ? xB : outB;
            scatter_add<<<4096, 256, 0, stream>>>(fB, attBA, eBA, E, msgA);
            scatter_add<<<4096, 256, 0, stream>>>(fA, attAB, eAB, E, msgB);
            combine<<<2048, 256, 0, stream>>>((const float4*)xA, (const float4*)msgA,
                                              alph, (float4*)outA, NA * D / 4);
            combine<<<2048, 256, 0, stream>>>((const float4*)xB, (const float4*)msgB,
                                              alph, (float4*)outB, NB * D / 4);
        }
    }
}

// Round 5
// 354.183 us; speedup vs baseline: 18.5869x; 1.1631x over previous
//
#include <hip/hip_runtime.h>
#include <math.h>

#define D 128
#define EPSV 1e-6f
#define CLIP_HI 1e6f
#define G 512            // colsum partial blocks
#define RPB 16           // rows per block in aggregate (256 threads / 16 lanes)
#define SCAN_ELEMS 1024  // elements per scan block (256 thr * 4)
#define HC 128           // chunks per (dir,range) for hist/fill partitioned kernels

// ---------------- bf16 helpers ----------------------------------------------
__device__ __forceinline__ float bf2f(unsigned short u) {
    return __uint_as_float(((unsigned)u) << 16);
}
__device__ __forceinline__ unsigned short f2bf(float f) {
    unsigned u = __float_as_uint(f);
    u = u + 0x7FFFu + ((u >> 16) & 1u);   // round-to-nearest-even
    return (unsigned short)(u >> 16);
}
// fma 8 bf16 elements (packed in uint4) * a into acc[8]
__device__ __forceinline__ void fma8(uint4 u, float a, float* acc) {
    acc[0] += __uint_as_float(u.x << 16) * a;
    acc[1] += __uint_as_float(u.x & 0xffff0000u) * a;
    acc[2] += __uint_as_float(u.y << 16) * a;
    acc[3] += __uint_as_float(u.y & 0xffff0000u) * a;
    acc[4] += __uint_as_float(u.z << 16) * a;
    acc[5] += __uint_as_float(u.z & 0xffff0000u) * a;
    acc[6] += __uint_as_float(u.w << 16) * a;
    acc[7] += __uint_as_float(u.w & 0xffff0000u) * a;
}

// -------- alpha partial colsums + x->bf16 conversion (fused, one x pass) ----
__global__ __launch_bounds__(256) void colsum_bf16(
        const float* __restrict__ xA, const float* __restrict__ xB,
        int NA, int NB, float* __restrict__ partA, float* __restrict__ partB,
        unsigned short* __restrict__ tblA, unsigned short* __restrict__ tblB) {
    __shared__ float4 sh[256];
    int tid = threadIdx.x;
    int c4  = tid & 31;   // float4 column chunk
    int rs  = tid >> 5;   // 0..7 row sub-slot
    float4 sa = make_float4(0.f, 0.f, 0.f, 0.f);
    float4 sb = make_float4(0.f, 0.f, 0.f, 0.f);
    for (int r = blockIdx.x * 8 + rs; r < NA; r += gridDim.x * 8) {
        float4 v = *reinterpret_cast<const float4*>(xA + (size_t)r * D + c4 * 4);
        sa.x += v.x; sa.y += v.y; sa.z += v.z; sa.w += v.w;
        ushort4 o; o.x = f2bf(v.x); o.y = f2bf(v.y); o.z = f2bf(v.z); o.w = f2bf(v.w);
        *reinterpret_cast<ushort4*>(tblA + (size_t)r * D + c4 * 4) = o;
    }
    for (int r = blockIdx.x * 8 + rs; r < NB; r += gridDim.x * 8) {
        float4 v = *reinterpret_cast<const float4*>(xB + (size_t)r * D + c4 * 4);
        sb.x += v.x; sb.y += v.y; sb.z += v.z; sb.w += v.w;
        ushort4 o; o.x = f2bf(v.x); o.y = f2bf(v.y); o.z = f2bf(v.z); o.w = f2bf(v.w);
        *reinterpret_cast<ushort4*>(tblB + (size_t)r * D + c4 * 4) = o;
    }
    sh[tid] = sa; __syncthreads();
    if (tid < 128) { sh[tid].x += sh[tid+128].x; sh[tid].y += sh[tid+128].y; sh[tid].z += sh[tid+128].z; sh[tid].w += sh[tid+128].w; } __syncthreads();
    if (tid < 64)  { sh[tid].x += sh[tid+64].x;  sh[tid].y += sh[tid+64].y;  sh[tid].z += sh[tid+64].z;  sh[tid].w += sh[tid+64].w;  } __syncthreads();
    if (tid < 32)  {
        float4 t = sh[tid]; float4 u = sh[tid+32];
        t.x += u.x; t.y += u.y; t.z += u.z; t.w += u.w;
        *reinterpret_cast<float4*>(partA + (size_t)blockIdx.x * D + tid * 4) = t;
    }
    __syncthreads();
    sh[tid] = sb; __syncthreads();
    if (tid < 128) { sh[tid].x += sh[tid+128].x; sh[tid].y += sh[tid+128].y; sh[tid].z += sh[tid+128].z; sh[tid].w += sh[tid+128].w; } __syncthreads();
    if (tid < 64)  { sh[tid].x += sh[tid+64].x;  sh[tid].y += sh[tid+64].y;  sh[tid].z += sh[tid+64].z;  sh[tid].w += sh[tid+64].w;  } __syncthreads();
    if (tid < 32)  {
        float4 t = sh[tid]; float4 u = sh[tid+32];
        t.x += u.x; t.y += u.y; t.z += u.z; t.w += u.w;
        *reinterpret_cast<float4*>(partB + (size_t)blockIdx.x * D + tid * 4) = t;
    }
}

// ---------------- alpha: reduce partials + tiny MLP -------------------------
__global__ void compute_alpha(const float* __restrict__ partA, const float* __restrict__ partB,
                              int NA, int NB,
                              const float* __restrict__ fc1_w, const float* __restrict__ fc1_b,
                              const float* __restrict__ fc2_w, const float* __restrict__ fc2_b,
                              float* __restrict__ alpha_out) {
    __shared__ float g[D];
    __shared__ float h[D];
    int c = threadIdx.x;  // 0..127
    float sa = 0.f, sb = 0.f;
    #pragma unroll 4
    for (int b = 0; b < G; ++b) {
        sa += partA[(size_t)b * D + c];
        sb += partB[(size_t)b * D + c];
    }
    g[c] = 0.5f * (sa / (float)NA + sb / (float)NB);
    __syncthreads();
    float acc = fc1_b[c];
    for (int k = 0; k < D; ++k) acc += g[k] * fc1_w[(size_t)c * D + k];
    h[c] = tanhf(acc);
    __syncthreads();
    if (c == 0) {
        float a = fc2_b[0];
        for (int k = 0; k < D; ++k) a += h[k] * fc2_w[k];
        a = 1.f / (1.f + expf(-a));
        a = fminf(fmaxf(a, EPSV), 1.f - EPSV);
        *alpha_out = a;
    }
}

// ---------------- CSR build (XCD-range-partitioned) --------------------------
// edge layout: edges[0..E) = src, edges[E..2E) = dst
// blockIdx&7 = dst-range (maps to one XCD under round-robin), bit3 = direction.
__global__ __launch_bounds__(256) void hist_part(
        const int* __restrict__ eA, int* __restrict__ countsA, int NA,
        const int* __restrict__ eB, int* __restrict__ countsB, int NB, int E) {
    int b = blockIdx.x;
    int range = b & 7;
    int dir   = (b >> 3) & 1;
    int chunk = b >> 4;
    const int* e = dir ? eB : eA;
    int* counts  = dir ? countsB : countsA;
    int N        = dir ? NB : NA;
    int lo = (int)((long)range * N >> 3), hi = (int)((long)(range + 1) * N >> 3);
    for (int i = chunk * 256 + threadIdx.x; i < E; i += HC * 256) {
        int dst = e[E + i];
        if (dst >= lo && dst < hi) atomicAdd(&counts[dst], 1);
    }
}

__global__ __launch_bounds__(256) void fill_part(
        const int* __restrict__ eA, const float* __restrict__ attA,
        int* __restrict__ curA, int2* __restrict__ csrA, int NA,
        const int* __restrict__ eB, const float* __restrict__ attB,
        int* __restrict__ curB, int2* __restrict__ csrB, int NB, int E) {
    int b = blockIdx.x;
    int range = b & 7;
    int dir   = (b >> 3) & 1;
    int chunk = b >> 4;
    const int* e; const float* att; int* cur; int2* csr; int N;
    if (dir == 0) { e = eA; att = attA; cur = curA; csr = csrA; N = NA; }
    else          { e = eB; att = attB; cur = curB; csr = csrB; N = NB; }
    int lo = (int)((long)range * N >> 3), hi = (int)((long)(range + 1) * N >> 3);
    for (int i = chunk * 256 + threadIdx.x; i < E; i += HC * 256) {
        int dst = e[E + i];
        if (dst >= lo && dst < hi) {
            int pos = atomicAdd(&cur[dst], 1);
            int2 v; v.x = e[i]; v.y = __float_as_int(att[i]);
            csr[pos] = v;
        }
    }
}

// ---- 3-phase parallel exclusive scan over two arrays (A then B blocks) -----
__global__ void scan_p1(const int* __restrict__ cA, int NAe, int nbA, int* __restrict__ bsA,
                        const int* __restrict__ cB, int NBe, int* __restrict__ bsB) {
    const int* c; int N; int* bs; int b;
    if ((int)blockIdx.x < nbA) { c = cA; N = NAe; bs = bsA; b = blockIdx.x; }
    else                       { c = cB; N = NBe; bs = bsB; b = blockIdx.x - nbA; }
    __shared__ int red[256];
    int tid = threadIdx.x;
    int base = b * SCAN_ELEMS + tid * 4;
    int s = 0;
    #pragma unroll
    for (int i = 0; i < 4; ++i) { int idx = base + i; if (idx < N) s += c[idx]; }
    red[tid] = s;
    __syncthreads();
    for (int off = 128; off > 0; off >>= 1) {
        if (tid < off) red[tid] += red[tid + off];
        __syncthreads();
    }
    if (tid == 0) bs[b] = red[0];
}

__global__ void scan_p2(int* __restrict__ bsA, int nbA, int* __restrict__ rpA, int NAe,
                        int* __restrict__ bsB, int nbB, int* __restrict__ rpB, int NBe) {
    int* bs; int nb; int* rp; int N;
    if (blockIdx.x == 0) { bs = bsA; nb = nbA; rp = rpA; N = NAe; }
    else                 { bs = bsB; nb = nbB; rp = rpB; N = NBe; }
    if (threadIdx.x == 0) {
        int run = 0;
        for (int i = 0; i < nb; ++i) { int t = bs[i]; bs[i] = run; run += t; }
        rp[N] = run;
    }
}

__global__ void scan_p3(int* __restrict__ cA, int NAe, const int* __restrict__ bsA, int nbA,
                        int* __restrict__ rpA,
                        int* __restrict__ cB, int NBe, const int* __restrict__ bsB,
                        int* __restrict__ rpB) {
    int* c; int N; const int* bs; int* rp; int b;
    if ((int)blockIdx.x < nbA) { c = cA; N = NAe; bs = bsA; rp = rpA; b = blockIdx.x; }
    else                       { c = cB; N = NBe; bs = bsB; rp = rpB; b = blockIdx.x - nbA; }
    __shared__ int sh[256];
    int tid = threadIdx.x;
    int base = b * SCAN_ELEMS + tid * 4;
    int v[4]; int s = 0;
    #pragma unroll
    for (int i = 0; i < 4; ++i) { int idx = base + i; v[i] = (idx < N) ? c[idx] : 0; s += v[i]; }
    sh[tid] = s;
    __syncthreads();
    for (int off = 1; off < 256; off <<= 1) {
        int t = (tid >= off) ? sh[tid - off] : 0;
        __syncthreads();
        sh[tid] += t;
        __syncthreads();
    }
    int excl = bs[b] + sh[tid] - s;
    #pragma unroll
    for (int i = 0; i < 4; ++i) {
        int idx = base + i;
        if (idx < N) { rp[idx] = excl; c[idx] = excl; excl += v[i]; }  // c becomes cursor
    }
}

// ---------------- fused gather-reduce + blend + clip ------------------------
// 16 lanes per dst row, uint4 (8 bf16) loads, 4-edge unroll, fp32 accumulate.
// LAST=0: write bf16 table for next hop. LAST=1: write fp32 d_out.
template <int LAST>
__global__ __launch_bounds__(256) void aggregate_combine(
        const int* __restrict__ row_ptr, const int2* __restrict__ csr,
        const unsigned short* __restrict__ src_feat,  // other side's cur (bf16)
        const float* __restrict__ feat0,              // this side's original x (fp32)
        const float* __restrict__ alpha_p,
        unsigned short* __restrict__ out_bf, float* __restrict__ out_f32, int N) {
    int row = blockIdx.x * RPB + (threadIdx.x >> 4);
    int lane = threadIdx.x & 15;          // 16 lanes * 8 elems = 128
    if (row >= N) return;
    int j = row_ptr[row], end = row_ptr[row + 1];
    float acc[8] = {0.f, 0.f, 0.f, 0.f, 0.f, 0.f, 0.f, 0.f};
    int off = lane * 8;
    for (; j + 3 < end; j += 4) {
        int2 c0 = csr[j], c1 = csr[j + 1], c2 = csr[j + 2], c3 = csr[j + 3];
        uint4 u0 = *reinterpret_cast<const uint4*>(src_feat + (size_t)c0.x * D + off);
        uint4 u1 = *reinterpret_cast<const uint4*>(src_feat + (size_t)c1.x * D + off);
        uint4 u2 = *reinterpret_cast<const uint4*>(src_feat + (size_t)c2.x * D + off);
        uint4 u3 = *reinterpret_cast<const uint4*>(src_feat + (size_t)c3.x * D + off);
        fma8(u0, __int_as_float(c0.y), acc);
        fma8(u1, __int_as_float(c1.y), acc);
        fma8(u2, __int_as_float(c2.y), acc);
        fma8(u3, __int_as_float(c3.y), acc);
    }
    for (; j < end; ++j) {
        int2 c0 = csr[j];
        uint4 u0 = *reinterpret_cast<const uint4*>(src_feat + (size_t)c0.x * D + off);
        fma8(u0, __int_as_float(c0.y), acc);
    }
    float al = alpha_p[0], bl = 1.f - al;
    float4 f0 = *reinterpret_cast<const float4*>(feat0 + (size_t)row * D + off);
    float4 f1 = *reinterpret_cast<const float4*>(feat0 + (size_t)row * D + off + 4);
    float r[8];
    r[0] = fminf(fmaxf(f0.x * al + acc[0] * bl, EPSV), CLIP_HI);
    r[1] = fminf(fmaxf(f0.y * al + acc[1] * bl, EPSV), CLIP_HI);
    r[2] = fminf(fmaxf(f0.z * al + acc[2] * bl, EPSV), CLIP_HI);
    r[3] = fminf(fmaxf(f0.w * al + acc[3] * bl, EPSV), CLIP_HI);
    r[4] = fminf(fmaxf(f1.x * al + acc[4] * bl, EPSV), CLIP_HI);
    r[5] = fminf(fmaxf(f1.y * al + acc[5] * bl, EPSV), CLIP_HI);
    r[6] = fminf(fmaxf(f1.z * al + acc[6] * bl, EPSV), CLIP_HI);
    r[7] = fminf(fmaxf(f1.w * al + acc[7] * bl, EPSV), CLIP_HI);
    if (LAST) {
        float4 o0 = make_float4(r[0], r[1], r[2], r[3]);
        float4 o1 = make_float4(r[4], r[5], r[6], r[7]);
        *reinterpret_cast<float4*>(out_f32 + (size_t)row * D + off) = o0;
        *reinterpret_cast<float4*>(out_f32 + (size_t)row * D + off + 4) = o1;
    } else {
        uint4 o;
        o.x = (unsigned)f2bf(r[0]) | ((unsigned)f2bf(r[1]) << 16);
        o.y = (unsigned)f2bf(r[2]) | ((unsigned)f2bf(r[3]) << 16);
        o.z = (unsigned)f2bf(r[4]) | ((unsigned)f2bf(r[5]) << 16);
        o.w = (unsigned)f2bf(r[6]) | ((unsigned)f2bf(r[7]) << 16);
        *reinterpret_cast<uint4*>(out_bf + (size_t)row * D + off) = o;
    }
}

// ---------------- fallback (atomic scatter) kernels --------------------------
__global__ void scatter_add(const float* __restrict__ cur, const float* __restrict__ att,
                            const int* __restrict__ edges, int E,
                            float* __restrict__ msg) {
    const long long total = (long long)E * (D / 4);
    long long stride = (long long)gridDim.x * blockDim.x;
    for (long long idx = (long long)blockIdx.x * blockDim.x + threadIdx.x;
         idx < total; idx += stride) {
        int e  = (int)(idx >> 5);
        int ch = (int)(idx & 31);
        int src = edges[e];
        int dst = edges[E + e];
        float a = att[e];
        const float4 v = *reinterpret_cast<const float4*>(cur + (size_t)src * D + ch * 4);
        float* p = msg + (size_t)dst * D + ch * 4;
        atomicAdd(p + 0, v.x * a);
        atomicAdd(p + 1, v.y * a);
        atomicAdd(p + 2, v.z * a);
        atomicAdd(p + 3, v.w * a);
    }
}

__global__ void combine(const float4* __restrict__ feat0, const float4* __restrict__ msg,
                        const float* __restrict__ alpha_p, float4* __restrict__ out, int n4) {
    float a = alpha_p[0];
    float b = 1.f - a;
    int stride = gridDim.x * blockDim.x;
    for (int i = blockIdx.x * blockDim.x + threadIdx.x; i < n4; i += stride) {
        float4 f = feat0[i];
        float4 m = msg[i];
        float4 r;
        r.x = fminf(fmaxf(f.x * a + m.x * b, EPSV), CLIP_HI);
        r.y = fminf(fmaxf(f.y * a + m.y * b, EPSV), CLIP_HI);
        r.z = fminf(fmaxf(f.z * a + m.z * b, EPSV), CLIP_HI);
        r.w = fminf(fmaxf(f.w * a + m.w * b, EPSV), CLIP_HI);
        out[i] = r;
    }
}

extern "C" void kernel_launch(void* const* d_in, const int* in_sizes, int n_in,
                              void* d_out, int out_size, void* d_ws, size_t ws_size,
                              hipStream_t stream) {
    const float* xA    = (const float*)d_in[0];
    const float* xB    = (const float*)d_in[1];
    const float* attAB = (const float*)d_in[2];
    const float* attBA = (const float*)d_in[3];
    const float* fc1_w = (const float*)d_in[4];
    const float* fc1_b = (const float*)d_in[5];
    const float* fc2_w = (const float*)d_in[6];
    const float* fc2_b = (const float*)d_in[7];
    const int*   eAB   = (const int*)d_in[8];   // src in A, dst in B
    const int*   eBA   = (const int*)d_in[9];   // src in B, dst in A

    const int NA = in_sizes[0] / D;
    const int NB = in_sizes[1] / D;
    const int E  = in_sizes[2];

    float* out  = (float*)d_out;
    float* outA = out;                      // [NA, D]
    float* outB = out + (size_t)NA * D;     // [NB, D]

    // ---- ws layout (CSR + bf16-table path) ----
    unsigned short* tbl0 = (unsigned short*)d_ws;               // (NA+NB)*D bf16
    unsigned short* tbl1 = tbl0 + (size_t)(NA + NB) * D;        // (NA+NB)*D bf16
    int2*  csrA   = (int2*)(tbl1 + (size_t)(NA + NB) * D);      // E
    int2*  csrB   = csrA + E;                                   // E
    float* partA  = (float*)(csrB + E);                         // G*D
    float* partB  = partA + (size_t)G * D;                      // G*D
    float* alpha  = partB + (size_t)G * D;                      // pad 4
    int*   row_ptrA = (int*)(alpha + 4);                        // NA+1
    int*   cursorA  = row_ptrA + (NA + 1);                      // NA
    int*   row_ptrB = cursorA + NA;                             // NB+1
    int*   cursorB  = row_ptrB + (NB + 1);                      // NB
    int*   bsA      = cursorB + NB;                             // 64
    int*   bsB      = bsA + 64;                                 // 64
    size_t needed = (size_t)((char*)(bsB + 64) - (char*)d_ws);

    unsigned short* tbl0A = tbl0;
    unsigned short* tbl0B = tbl0 + (size_t)NA * D;
    unsigned short* tbl1A = tbl1;
    unsigned short* tbl1B = tbl1 + (size_t)NA * D;

    if (ws_size >= needed) {
        // ---------------- CSR path ----------------
        colsum_bf16<<<G, 256, 0, stream>>>(xA, xB, NA, NB, partA, partB, tbl0A, tbl0B);
        compute_alpha<<<1, D, 0, stream>>>(partA, partB, NA, NB,
                                           fc1_w, fc1_b, fc2_w, fc2_b, alpha);

        hipMemsetAsync(cursorA, 0, (size_t)NA * sizeof(int), stream);
        hipMemsetAsync(cursorB, 0, (size_t)NB * sizeof(int), stream);
        hist_part<<<16 * HC, 256, 0, stream>>>(eBA, cursorA, NA, eAB, cursorB, NB, E);

        int nbA = (NA + SCAN_ELEMS - 1) / SCAN_ELEMS;
        int nbB = (NB + SCAN_ELEMS - 1) / SCAN_ELEMS;
        scan_p1<<<nbA + nbB, 256, 0, stream>>>(cursorA, NA, nbA, bsA, cursorB, NB, bsB);
        scan_p2<<<2, 64, 0, stream>>>(bsA, nbA, row_ptrA, NA, bsB, nbB, row_ptrB, NB);
        scan_p3<<<nbA + nbB, 256, 0, stream>>>(cursorA, NA, bsA, nbA, row_ptrA,
                                               cursorB, NB, bsB, row_ptrB);

        fill_part<<<16 * HC, 256, 0, stream>>>(eBA, attBA, cursorA, csrA, NA,
                                               eAB, attAB, cursorB, csrB, NB, E);

        int gA = (NA + RPB - 1) / RPB;
        int gB = (NB + RPB - 1) / RPB;
        // hop 0: tbl0 (x) -> tbl1
        aggregate_combine<0><<<gA, 256, 0, stream>>>(row_ptrA, csrA, tbl0B, xA, alpha, tbl1A, nullptr, NA);
        aggregate_combine<0><<<gB, 256, 0, stream>>>(row_ptrB, csrB, tbl0A, xB, alpha, tbl1B, nullptr, NB);
        // hop 1: tbl1 -> tbl0
        aggregate_combine<0><<<gA, 256, 0, stream>>>(row_ptrA, csrA, tbl1B, xA, alpha, tbl0A, nullptr, NA);
        aggregate_combine<0><<<gB, 256, 0, stream>>>(row_ptrB, csrB, tbl1A, xB, alpha, tbl0B, nullptr, NB);
        // hop 2: tbl0 -> d_out (fp32)
        aggregate_combine<1><<<gA, 256, 0, stream>>>(row_ptrA, csrA, tbl0B, xA, alpha, nullptr, outA, NA);
        aggregate_combine<1><<<gB, 256, 0, stream>>>(row_ptrB, csrB, tbl0A, xB, alpha, nullptr, outB, NB);
    } else {
        // ---------------- fallback: atomic scatter path ----------------
        float* msgA  = (float*)d_ws;
        float* msgB  = msgA + (size_t)NA * D;
        float* pA    = msgB + (size_t)NB * D;
        float* pB    = pA + (size_t)G * D;
        float* alph  = pB + (size_t)G * D;

        colsum_bf16<<<G, 256, 0, stream>>>(xA, xB, NA, NB, pA, pB,
                                           (unsigned short*)msgA, (unsigned short*)msgB);
        compute_alpha<<<1, D, 0, stream>>>(pA, pB, NA, NB,
                                           fc1_w, fc1_b, fc2_w, fc2_b, alph);

        const size_t msgBytes = ((size_t)NA + (size_t)NB) * D * sizeof(float);
        for (int hop = 0; hop < 3; ++hop) {
            hipMemsetAsync(msgA, 0, msgBytes, stream);
            const float* fA = (hop == 0) ? xA : outA;
            const float* fB = (hop == 0) ? xB : outB;
            scatter_add<<<4096, 256, 0, stream>>>(fB, attBA, eBA, E, msgA);
            scatter_add<<<4096, 256, 0, stream>>>(fA, attAB, eAB, E, msgB);
            combine<<<2048, 256, 0, stream>>>((const float4*)xA, (const float4*)msgA,
                                              alph, (float4*)outA, NA * D / 4);
            combine<<<2048, 256, 0, stream>>>((const float4*)xB, (const float4*)msgB,
                                              alph, (float4*)outB, NB * D / 4);
        }
    }
}